// Round 11
// baseline (554.413 us; speedup 1.0000x reference)
//
#include <hip/hip_runtime.h>
#include <hip/hip_bf16.h>

// Problem constants
#define NN    8192
#define FEAT  64
#define HIDD  128
#define EMBD  128

typedef __bf16 bf16x8 __attribute__((ext_vector_type(8)));
typedef float  f32x4  __attribute__((ext_vector_type(4)));

template<int AUX>
__device__ __forceinline__ void gload16(const void* g, void* l) {
    __builtin_amdgcn_global_load_lds(
        (const __attribute__((address_space(1))) void*)g,
        (__attribute__((address_space(3))) void*)l, 16, 0, AUX);
}

// ---------------------------------------------------------------------------
// proj_pack: V_r = X @ W_r^T into MFMA B-fragment layout (layer 1, X = H f32)
//   Vp elem ((r<<20) + kb32*4096 + n*512 + l*8 + j) = V_r[kb32*32+(l>>4)*8+j][n*16+(l&15)]
// 16-row blocks (512 blocks = 2/CU) for TLP; thread (c,h) covers rows h*8..h*8+7,
// col c -> exactly one bf16x8 store per r.
// ---------------------------------------------------------------------------
template<int KIN>
__global__ __launch_bounds__(256) void proj_pack(
    const float* __restrict__ X, const float* __restrict__ W0,
    const float* __restrict__ W1, const float* __restrict__ W2,
    __bf16* __restrict__ Vp)
{
    __shared__ float sx[16 * KIN];
    const int kb  = blockIdx.x;               // 16-row block, 0..511
    const int tid = threadIdx.x;
    {
        const f32x4* src = (const f32x4*)(X + (size_t)kb * 16 * KIN);
#pragma unroll
        for (int i = 0; i < 16 * KIN / 4 / 256; ++i)
            ((f32x4*)sx)[tid + i * 256] = src[tid + i * 256];
    }
    __syncthreads();

    const int c = tid & 127, h = tid >> 7;
    const int n = c >> 4, c15 = c & 15;
    const int l = ((kb * 2 + h) & 3) * 16 + c15;   // lane within fragment
    const int kb32 = kb >> 1;
    const float* Ws[3] = {W0, W1, W2};
#pragma unroll
    for (int r = 0; r < 3; ++r) {
        f32x4 wreg[KIN / 4];
        const f32x4* wrow = (const f32x4*)(Ws[r] + (size_t)c * KIN);
#pragma unroll
        for (int j = 0; j < KIN / 4; ++j) wreg[j] = wrow[j];
        bf16x8 b;
#pragma unroll
        for (int i = 0; i < 8; ++i) {
            const f32x4* xr = (const f32x4*)(sx + (h * 8 + i) * KIN);
            float s = 0.f;
#pragma unroll
            for (int j = 0; j < KIN / 4; ++j) {
                f32x4 xv = xr[j];
                s += xv[0]*wreg[j][0] + xv[1]*wreg[j][1] + xv[2]*wreg[j][2] + xv[3]*wreg[j][3];
            }
            b[i] = (__bf16)s;
        }
        *(bf16x8*)(Vp + ((size_t)r << 20) + kb32 * 4096 + n * 512 + l * 8) = b;
    }
}

// ---------------------------------------------------------------------------
// proj_hid: layer-2 projection FUSED with layer-1 reduce+relu (H1 in LDS only).
// 16-row blocks (512 blocks). P slab loads are nontemporal (no reuse).
// ---------------------------------------------------------------------------
__global__ __launch_bounds__(256) void proj_hid(
    const float* __restrict__ P, const float* __restrict__ b1,
    const float* __restrict__ W0, const float* __restrict__ W1,
    const float* __restrict__ W2, __bf16* __restrict__ Vp)
{
    __shared__ float sx[16 * HIDD];     // 8 KB
    const int kb  = blockIdx.x;         // 0..511
    const int tid = threadIdx.x;
    // reduce 8 P slabs + bias + relu for rows kb*16..+15 (2048 floats)
#pragma unroll
    for (int j = 0; j < 2; ++j) {
        const int idx = tid * 8 + j * 4;                 // flat in [0,2048)
        f32x4 s = *(const f32x4*)(b1 + (idx & 127));
#pragma unroll
        for (int p = 0; p < 8; ++p)
            s += __builtin_nontemporal_load(
                (const f32x4*)(P + (size_t)p * (NN * 128) + (size_t)kb * 2048 + idx));
#pragma unroll
        for (int cc = 0; cc < 4; ++cc) s[cc] = s[cc] > 0.f ? s[cc] : 0.f;
        *(f32x4*)(sx + idx) = s;
    }
    __syncthreads();

    const int c = tid & 127, h = tid >> 7;
    const int n = c >> 4, c15 = c & 15;
    const int l = ((kb * 2 + h) & 3) * 16 + c15;
    const int kb32 = kb >> 1;
    const float* Ws[3] = {W0, W1, W2};
#pragma unroll
    for (int r = 0; r < 3; ++r) {
        f32x4 wreg[HIDD / 4];
        const f32x4* wrow = (const f32x4*)(Ws[r] + (size_t)c * HIDD);
#pragma unroll
        for (int j = 0; j < HIDD / 4; ++j) wreg[j] = wrow[j];
        bf16x8 b;
#pragma unroll
        for (int i = 0; i < 8; ++i) {
            const f32x4* xr = (const f32x4*)(sx + (h * 8 + i) * HIDD);
            float s = 0.f;
#pragma unroll
            for (int j = 0; j < HIDD / 4; ++j) {
                f32x4 xv = xr[j];
                s += xv[0]*wreg[j][0] + xv[1]*wreg[j][1] + xv[2]*wreg[j][2] + xv[3]*wreg[j][3];
            }
            b[i] = (__bf16)s;
        }
        *(bf16x8*)(Vp + ((size_t)r << 20) + kb32 * 4096 + n * 512 + l * 8) = b;
    }
}

// ---------------------------------------------------------------------------
// gemm_AV (proven 206 us / 3.9 TB/s demand-side — at the measured read wall):
// BM=64 x BN=128, BK=32; 4 waves; 2x16KB LDS bufs; counted vmcnt(4); raw
// s_barrier; lgkmcnt guard. A staged NT (aux=2) with XOR 16B-block swizzle;
// P stores nontemporal. Grid (128 mt, 8 ch) = 1024 blocks = 4/CU.
// ---------------------------------------------------------------------------
__global__ __launch_bounds__(256, 4) void gemm_AV(
    const float* __restrict__ A0, const float* __restrict__ A1,
    const float* __restrict__ A2,
    const __bf16* __restrict__ Vp, float* __restrict__ P)
{
    __shared__ __align__(16) unsigned char sbuf[2][16384];  // [A 8KB f32][B 8KB]

    const int mt = blockIdx.x, ch = blockIdx.y;
    const int tid = threadIdx.x;
    const int w = tid >> 6, l = tid & 63;
    const int l15 = l & 15, l4 = l >> 4;
    const int rowblk = mt * 64;

    f32x4 acc[8];
#pragma unroll
    for (int n = 0; n < 8; n++) acc[n] = (f32x4){0.f, 0.f, 0.f, 0.f};

    const int srow = l >> 3;                 // row-within-8-group == (row&7)
    const int sblk = (l & 7) ^ srow;         // inverse-swizzled source 16B block

    auto stage = [&](int t) {
        const int r = t >> 5, kk = t & 31;
        const float* Ar = (r == 0) ? A0 : (r == 1) ? A1 : A2;
        const int kglob = ch * 1024 + kk * 32;
        unsigned char* dst = sbuf[t & 1];
        const float* abase = Ar + (size_t)(rowblk + w * 16 + srow) * NN + kglob + sblk * 4;
#pragma unroll
        for (int j = 0; j < 2; ++j)
            gload16<2>(abase + (size_t)j * 8 * NN, dst + w * 2048 + j * 1024 + l * 16);
        const char* bsrc = (const char*)(Vp + ((size_t)r << 20)) + (size_t)(ch * 32 + kk) * 8192;
#pragma unroll
        for (int q = 0; q < 2; ++q)
            gload16<0>(bsrc + (w * 2 + q) * 1024 + l * 16,
                       dst + 8192 + (w * 2 + q) * 1024 + l * 16);
    };

    stage(0); stage(1);

    for (int t = 0; t < 96; ++t) {
        if (t < 95) asm volatile("s_waitcnt vmcnt(4)" ::: "memory");
        else        asm volatile("s_waitcnt vmcnt(0)" ::: "memory");
        __builtin_amdgcn_s_barrier();

        const unsigned char* buf = sbuf[t & 1];
        const int b0 = (2 * l4) ^ (l15 & 7);
        f32x4 lo = *(const f32x4*)(buf + w * 2048 + l15 * 128 + b0 * 16);
        f32x4 hi = *(const f32x4*)(buf + w * 2048 + l15 * 128 + (b0 ^ 1) * 16);
        bf16x8 af;
        af[0] = (__bf16)lo[0]; af[1] = (__bf16)lo[1];
        af[2] = (__bf16)lo[2]; af[3] = (__bf16)lo[3];
        af[4] = (__bf16)hi[0]; af[5] = (__bf16)hi[1];
        af[6] = (__bf16)hi[2]; af[7] = (__bf16)hi[3];
        bf16x8 bfr[8];
#pragma unroll
        for (int n = 0; n < 8; ++n)
            bfr[n] = *(const bf16x8*)(buf + 8192 + n * 1024 + l * 16);
#pragma unroll
        for (int n = 0; n < 8; ++n)
            acc[n] = __builtin_amdgcn_mfma_f32_16x16x32_bf16(af, bfr[n], acc[n], 0, 0, 0);

        asm volatile("s_waitcnt lgkmcnt(0)" ::: "memory");
        __builtin_amdgcn_s_barrier();
        if (t < 94) stage(t + 2);
    }

    // C/D layout: col = lane&15, row = (lane>>4)*4 + i ; NT stores
    float* Pp = P + (size_t)ch * NN * 128;
#pragma unroll
    for (int n = 0; n < 8; n++) {
        int col = n * 16 + l15;
#pragma unroll
        for (int i = 0; i < 4; i++) {
            int row = rowblk + w * 16 + l4 * 4 + i;
            __builtin_nontemporal_store(acc[n][i], &Pp[(size_t)row * 128 + col]);
        }
    }
}

// ---------------------------------------------------------------------------
// reduce_z: sum 8 partial slabs + bias -> Zout (f32) and Zb (bf16)
// ---------------------------------------------------------------------------
__global__ __launch_bounds__(256) void reduce_z(
    const float* __restrict__ P, const float* __restrict__ bias,
    float* __restrict__ Zout, __bf16* __restrict__ Zb)
{
    size_t g = (size_t)blockIdx.x * 256 + threadIdx.x;
    size_t idx4 = g * 4;
    f32x4 s = *(const f32x4*)(bias + (idx4 & 127));
#pragma unroll
    for (int p = 0; p < 8; p++)
        s += __builtin_nontemporal_load((const f32x4*)(P + (size_t)p * (NN * 128) + idx4));
    *(f32x4*)(Zout + idx4) = s;
#pragma unroll
    for (int c = 0; c < 4; c++) Zb[idx4 + c] = (__bf16)s[c];
}

// ---------------------------------------------------------------------------
// zzt: A_hat = Z @ Z^T with LDS-transposed, write-coalesced NT epilogue.
// ---------------------------------------------------------------------------
__global__ __launch_bounds__(256) void zzt(
    const __bf16* __restrict__ Zb, float* __restrict__ Out)
{
    __shared__ float tz[4][32][132];

    const int bx = blockIdx.x;
    const int by = blockIdx.y;
    const int tid = threadIdx.x;
    const int w = tid >> 6, l = tid & 63;
    const int l15 = l & 15, l4 = l >> 4;
    const int rowbase = by * 128 + w * 32;
    const int colbase = bx * 128;

    f32x4 acc[2][8];
#pragma unroll
    for (int m = 0; m < 2; m++)
#pragma unroll
        for (int n = 0; n < 8; n++) acc[m][n] = (f32x4){0.f, 0.f, 0.f, 0.f};

#pragma unroll
    for (int ks = 0; ks < 128; ks += 32) {
        bf16x8 af[2];
#pragma unroll
        for (int m = 0; m < 2; m++)
            af[m] = *(const bf16x8*)(Zb + (size_t)(rowbase + m * 16 + l15) * 128 + ks + l4 * 8);
#pragma unroll
        for (int n = 0; n < 8; n++) {
            bf16x8 bfr = *(const bf16x8*)(Zb + (size_t)(colbase + n * 16 + l15) * 128 + ks + l4 * 8);
            acc[0][n] = __builtin_amdgcn_mfma_f32_16x16x32_bf16(af[0], bfr, acc[0][n], 0, 0, 0);
            acc[1][n] = __builtin_amdgcn_mfma_f32_16x16x32_bf16(af[1], bfr, acc[1][n], 0, 0, 0);
        }
    }

#pragma unroll
    for (int m = 0; m < 2; m++)
#pragma unroll
        for (int n = 0; n < 8; n++)
#pragma unroll
            for (int i = 0; i < 4; i++)
                tz[w][m * 16 + l4 * 4 + i][n * 16 + l15] = acc[m][n][i];
    asm volatile("s_waitcnt lgkmcnt(0)" ::: "memory");

    const int rp = l >> 5;
    const int c4 = l & 31;
#pragma unroll
    for (int q = 0; q < 16; ++q) {
        f32x4 v = *(const f32x4*)&tz[w][q * 2 + rp][c4 * 4];
        __builtin_nontemporal_store(v,
            (f32x4*)(Out + (size_t)(rowbase + q * 2 + rp) * NN + colbase + c4 * 4));
    }
}

// ---------------------------------------------------------------------------
extern "C" void kernel_launch(void* const* d_in, const int* in_sizes, int n_in,
                              void* d_out, int out_size, void* d_ws, size_t ws_size,
                              hipStream_t stream)
{
    // setup_inputs() order: H, A_buys, A_views, A_rates,
    //   W1_0, W2_0, W1_1, W2_1, W1_2, W2_2, b1, b2
    const float* H    = (const float*)d_in[0];
    const float* A0   = (const float*)d_in[1];
    const float* A1   = (const float*)d_in[2];
    const float* A2   = (const float*)d_in[3];
    const float* W1_0 = (const float*)d_in[4];
    const float* W2_0 = (const float*)d_in[5];
    const float* W1_1 = (const float*)d_in[6];
    const float* W2_1 = (const float*)d_in[7];
    const float* W1_2 = (const float*)d_in[8];
    const float* W2_2 = (const float*)d_in[9];
    const float* b1   = (const float*)d_in[10];
    const float* b2   = (const float*)d_in[11];

    float* Zout = (float*)d_out;                     // [8192][128]
    float* Ahat = (float*)d_out + (size_t)NN * EMBD; // [8192][8192]

    char* ws = (char*)d_ws;
    float*  P   = (float*)ws;                         // 32 MB partials (8 slabs)
    __bf16* Vp  = (__bf16*)(ws + ((size_t)32 << 20)); //  6 MB packed V (3 x 2MB)
    __bf16* Zb  = (__bf16*)(ws + ((size_t)38 << 20)); //  2 MB

    // Layer 1
    proj_pack<FEAT><<<512, 256, 0, stream>>>(H, W1_0, W1_1, W1_2, Vp);
    gemm_AV<<<dim3(128, 8), 256, 0, stream>>>(A0, A1, A2, Vp, P);

    // Layer 2 (projection fused with layer-1 reduce+relu; H1 never hits HBM)
    proj_hid<<<512, 256, 0, stream>>>(P, b1, W2_0, W2_1, W2_2, Vp);
    gemm_AV<<<dim3(128, 8), 256, 0, stream>>>(A0, A1, A2, Vp, P);
    reduce_z<<<1024, 256, 0, stream>>>(P, b2, Zout, Zb);

    // Decoder
    zzt<<<dim3(64, 64), 256, 0, stream>>>(Zb, Ahat);
}